// Round 3
// baseline (2367.876 us; speedup 1.0000x reference)
//
#include <hip/hip_runtime.h>
#include <math.h>

#define NB 256
#define NO 32
#define NEE 32
#define NT 16
#define THREADS 512

typedef const float* __restrict__ fp;

struct Params {
  fp z;
  fp ee1w, ee1b, ee2w, ee2b, ee3w, ee3b;
  fp ne1w, ne1b, ne2w, ne2b, ne3w, ne3b, ne4w, ne4b;
  fp le1w, le1b, le2w, le2b, le3w, le3b;
  fp lt1w, lt1b, lt2w, lt2b, lt3w, lt3b, lt4w, lt4b, lt5w, lt5b;
  float* out;
  int tf;
};

__device__ __forceinline__ float frelu(float x) { return x > 0.f ? x : 0.f; }

// LDS float offsets (16384 floats = 64 KiB)
#define OFF_UT  0       // 2048: u transposed [h=64][node=32]
#define OFF_VT  2048    // 2048: v transposed [h=64][node=32]
#define OFF_AGT 4096    // 2048: agg transposed [c=64][node=32]
#define OFF_A   6144    // 4096: weight slot A
#define OFF_B   10240   // 4096: weight slot B
#define OFF_BN  14336   // 2048: 8 waves x 4 x 64 wave-private bounce

// Single shared allocation, reachable from noinline fns with addrspace intact.
__device__ __forceinline__ float* get_lds() {
  __shared__ float L[16384];
  return L;
}

__device__ __forceinline__ void stage4096(float* dst, const float* __restrict__ src, int tid) {
#pragma unroll
  for (int r = 0; r < 2; ++r) {
    int i4 = tid + r * THREADS;
    *(float4*)(dst + i4 * 4) = *(const float4*)(src + i4 * 4);
  }
}
__device__ __forceinline__ void stageN(float* dst, const float* __restrict__ src, int nf4, int tid) {
  for (int i4 = tid; i4 < nf4; i4 += THREADS)
    *(float4*)(dst + i4 * 4) = *(const float4*)(src + i4 * 4);
}

// 4-row dense, natural [k][ldw] weights in LDS, x rows broadcast from LDS.
template<int KC>
__device__ __forceinline__ void dense4L(const float* x0, const float* x1,
                                        const float* x2, const float* x3,
                                        const float* w, int ldw, int col, float o[4]) {
#pragma unroll
  for (int kc = 0; kc < KC; ++kc) {
    float w0 = w[(4 * kc + 0) * ldw + col];
    float w1 = w[(4 * kc + 1) * ldw + col];
    float w2 = w[(4 * kc + 2) * ldw + col];
    float w3 = w[(4 * kc + 3) * ldw + col];
    float4 a = *(const float4*)(x0 + 4 * kc);
    float4 b = *(const float4*)(x1 + 4 * kc);
    float4 c = *(const float4*)(x2 + 4 * kc);
    float4 d = *(const float4*)(x3 + 4 * kc);
    o[0] = fmaf(a.x, w0, o[0]); o[0] = fmaf(a.y, w1, o[0]); o[0] = fmaf(a.z, w2, o[0]); o[0] = fmaf(a.w, w3, o[0]);
    o[1] = fmaf(b.x, w0, o[1]); o[1] = fmaf(b.y, w1, o[1]); o[1] = fmaf(b.z, w2, o[1]); o[1] = fmaf(b.w, w3, o[1]);
    o[2] = fmaf(c.x, w0, o[2]); o[2] = fmaf(c.y, w1, o[2]); o[2] = fmaf(c.z, w2, o[2]); o[2] = fmaf(c.w, w3, o[2]);
    o[3] = fmaf(d.x, w0, o[3]); o[3] = fmaf(d.y, w1, o[3]); o[3] = fmaf(d.z, w2, o[3]); o[3] = fmaf(d.w, w3, o[3]);
  }
}

// Same, but x comes from a TRANSPOSED [k][32] buffer (scalar broadcast reads).
template<int KC>
__device__ __forceinline__ void dense4T(const float* xt, int r0, int r1, int r2, int r3,
                                        const float* w, int ldw, int col, float o[4]) {
#pragma unroll
  for (int kc = 0; kc < KC; ++kc) {
#pragma unroll
    for (int j = 0; j < 4; ++j) {
      int k = 4 * kc + j;
      float wk = w[k * ldw + col];
      o[0] = fmaf(xt[k * 32 + r0], wk, o[0]);
      o[1] = fmaf(xt[k * 32 + r1], wk, o[1]);
      o[2] = fmaf(xt[k * 32 + r2], wk, o[2]);
      o[3] = fmaf(xt[k * 32 + r3], wk, o[3]);
    }
  }
}

// Pair MLP, lane = one pair. Weights/biases are wave-uniform -> scalar loads.
// LDS: reads UT/VT gathers (conflict-free), atomics into transposed AGT.
__device__ __noinline__ void pair_mlp(int lane, int wave,
                                      fp w2, fp w3, fp b1, fp b2, fp b3) {
  float* lds = get_lds();
  const float* UT = lds + OFF_UT;
  const float* VT = lds + OFF_VT;
  float* AGT = lds + OFF_AGT;

  int p = wave + 8 * lane;              // strided pair assignment, 496 real
  bool real = (p < 496);
  int pc = real ? p : 0;
  float d = (float)(3969 - 8 * pc);     // (63-2i)^2 at row boundaries (exact)
  int i = (int)((63.0f - sqrtf(d)) * 0.5f);
  int off = i * (63 - i) / 2;
  if (pc < off) { --i; off = i * (63 - i) / 2; }
  else { int off2 = (i + 1) * (62 - i) / 2; if (pc >= off2) { ++i; off = off2; } }
  int j = pc - off + i + 1;

  float acc[64];
#pragma unroll
  for (int c = 0; c < 64; ++c) acc[c] = b2[c];
#pragma unroll 2
  for (int h = 0; h < 64; ++h) {
    float x = UT[h * 32 + i] + VT[h * 32 + j] + b1[h];
    x = fmaxf(x, 0.f);
    const float* wr = w2 + h * 64;
#pragma unroll
    for (int c = 0; c < 64; ++c) acc[c] = fmaf(x, wr[c], acc[c]);
  }
  float e[64];
#pragma unroll
  for (int c = 0; c < 64; ++c) e[c] = b3[c];
#pragma unroll
  for (int h = 0; h < 64; ++h) {
    float x = fmaxf(acc[h], 0.f);
    const float* wr = w3 + h * 64;
#pragma unroll
    for (int c = 0; c < 64; ++c) e[c] = fmaf(x, wr[c], e[c]);
  }
  if (real) {
#pragma unroll
    for (int c = 0; c < 64; ++c) {
      atomicAdd(&AGT[c * 32 + i],  e[c]);
      atomicAdd(&AGT[c * 32 + j], -e[c]);
    }
  }
}

__global__ __launch_bounds__(THREADS, 2) void rld_kernel(Params P) {
  float* lds = get_lds();
  const int b = blockIdx.x;
  const int tid = (int)threadIdx.x;
  const int lane = tid & 63;
  const int wave = tid >> 6;
  const int cc = lane & 31;
  const int c16 = lane & 15;

  float* UT = lds + OFF_UT;
  float* VT = lds + OFF_VT;
  float* AGT = lds + OFF_AGT;
  float* slA = lds + OFF_A;
  float* slB = lds + OFF_B;
  float* sBn = lds + OFF_BN + wave * 256;   // wave-private bounce (4 rows x 64)
  const int i0 = wave, i1 = wave + 8, i2 = wave + 16, i3 = wave + 24;
  const float* zb = P.z + (size_t)b * NT * NO * NEE;
  const float4 z4 = make_float4(0.f, 0.f, 0.f, 0.f);

  // ===== A1: src[32,512] @ {ee1a, ee1b, ne1a} via staged chunks =====
  float au[4] = {0, 0, 0, 0}, av[4] = {0, 0, 0, 0}, s1r[4] = {0, 0, 0, 0};
  for (int qq = 0; qq < 4; ++qq) {
    __syncthreads();
    for (int idx = tid; idx < 4096; idx += THREADS) {   // src quarter -> [0,4096)
      int i = idx >> 7, kk = idx & 127;
      int k = qq * 128 + kk, t = k >> 5, e = k & 31;
      float v = zb[(t * NO + i) * NEE + e];
      if (t > 0) v -= zb[((t - 1) * NO + i) * NEE + e];
      lds[i * 128 + kk] = v;
    }
    for (int c = 0; c < 4; ++c) {
      __syncthreads();
      {
        int r0 = qq * 128 + c * 32;
        int kk = tid >> 4, o4 = (tid & 15) << 2;
        *(float4*)(slA + kk * 64 + o4)        = *(const float4*)(P.ee1w + (r0 + kk) * 64 + o4);
        *(float4*)(slA + 2048 + kk * 64 + o4) = *(const float4*)(P.ee1w + (512 + r0 + kk) * 64 + o4);
        *(float4*)(slB + kk * 64 + o4)        = *(const float4*)(P.ne1w + (r0 + kk) * 64 + o4);
      }
      __syncthreads();
      const float* x0 = lds + i0 * 128 + c * 32;
      const float* x1 = lds + i1 * 128 + c * 32;
      const float* x2 = lds + i2 * 128 + c * 32;
      const float* x3 = lds + i3 * 128 + c * 32;
      dense4L<8>(x0, x1, x2, x3, slA, 64, lane, au);
      dense4L<8>(x0, x1, x2, x3, slA + 2048, 64, lane, av);
      dense4L<8>(x0, x1, x2, x3, slB, 64, lane, s1r);
    }
  }
  __syncthreads();                        // all src/slot reads done
  UT[lane * 32 + i0] = au[0]; UT[lane * 32 + i1] = au[1];
  UT[lane * 32 + i2] = au[2]; UT[lane * 32 + i3] = au[3];
  VT[lane * 32 + i0] = av[0]; VT[lane * 32 + i1] = av[1];
  VT[lane * 32 + i2] = av[2]; VT[lane * 32 + i3] = av[3];
  *(float4*)(AGT + (tid << 2)) = z4;      // zero 2048 floats
  stage4096(slA, P.ne1w + 512 * 64, tid); // ne1 agg-half (overlaps pair)
  stage4096(slB, P.ne2w, tid);
  __syncthreads();                        // UT/VT/AGT + slots visible

  // ===== A2: ee edge MLP =====
  pair_mlp(lane, wave, P.ee2w, P.ee3w, P.ee1b, P.ee2b, P.ee3b);
  __syncthreads();                        // agg complete

  // ===== A3: ne node MLP -> zci[4] =====
  float zci[4];
  {
    float nb1 = P.ne1b[lane], nb2 = P.ne2b[lane];
    float nb3 = P.ne3b[cc],   nb4 = P.ne4b[cc];
    float o1[4] = {s1r[0] + nb1, s1r[1] + nb1, s1r[2] + nb1, s1r[3] + nb1};
    dense4T<16>(AGT, i0, i1, i2, i3, slA, 64, lane, o1);
    sBn[lane] = frelu(o1[0]); sBn[64 + lane] = frelu(o1[1]);
    sBn[128 + lane] = frelu(o1[2]); sBn[192 + lane] = frelu(o1[3]);
    float o2[4] = {nb2, nb2, nb2, nb2};
    dense4L<16>(sBn, sBn + 64, sBn + 128, sBn + 192, slB, 64, lane, o2);
    sBn[lane] = frelu(o2[0]); sBn[64 + lane] = frelu(o2[1]);
    sBn[128 + lane] = frelu(o2[2]); sBn[192 + lane] = frelu(o2[3]);
    __syncthreads();                      // ne1/ne2 slot readers done
    stageN(slA, P.ne3w, 512, tid);        // 64x32
    stageN(slA + 2048, P.ne4w, 256, tid); // 32x32
    __syncthreads();
    float o3[4] = {nb3, nb3, nb3, nb3};
    dense4L<16>(sBn, sBn + 64, sBn + 128, sBn + 192, slA, 32, cc, o3);
    sBn[cc] = frelu(o3[0]); sBn[64 + cc] = frelu(o3[1]);
    sBn[128 + cc] = frelu(o3[2]); sBn[192 + cc] = frelu(o3[3]);
    float o4[4] = {nb4, nb4, nb4, nb4};
    dense4L<8>(sBn, sBn + 64, sBn + 128, sBn + 192, slA + 2048, 32, cc, o4);
    zci[0] = (lane < 32) ? zb[(15 * NO + i0) * NEE + lane] : o4[0];
    zci[1] = (lane < 32) ? zb[(15 * NO + i1) * NEE + lane] : o4[1];
    zci[2] = (lane < 32) ? zb[(15 * NO + i2) * NEE + lane] : o4[2];
    zci[3] = (lane < 32) ? zb[(15 * NO + i3) * NEE + lane] : o4[3];
  }

  float lb1 = P.lt1b[lane], lb2 = P.lt2b[lane];
  float lb3 = P.lt3b[cc],   lb4 = P.lt4b[c16], lb5 = P.lt5b[lane];
  float* outb = P.out + (size_t)b * P.tf * NO * NEE;

  // ===== Phase B: t_future steps, 6 barriers/step =====
  for (int t = 0; t < P.tf; ++t) {
    __syncthreads();                      // S0: prior slot/UT/VT/AGT readers done
    stage4096(slA, P.le1w, tid);          // le1 rows 0..63  (u)
    stage4096(slB, P.le1w + 4096, tid);   // le1 rows 64..127 (v)
    *(float4*)(AGT + (tid << 2)) = z4;    // zero agg
    sBn[lane] = zci[0]; sBn[64 + lane] = zci[1];      // zc bounce (wave-local)
    sBn[128 + lane] = zci[2]; sBn[192 + lane] = zci[3];
    __syncthreads();                      // S1: le1 + agg-zero visible
    float ou[4] = {0, 0, 0, 0}, ov[4] = {0, 0, 0, 0};
    dense4L<16>(sBn, sBn + 64, sBn + 128, sBn + 192, slA, 64, lane, ou);
    dense4L<16>(sBn, sBn + 64, sBn + 128, sBn + 192, slB, 64, lane, ov);
    UT[lane * 32 + i0] = ou[0]; UT[lane * 32 + i1] = ou[1];
    UT[lane * 32 + i2] = ou[2]; UT[lane * 32 + i3] = ou[3];
    VT[lane * 32 + i0] = ov[0]; VT[lane * 32 + i1] = ov[1];
    VT[lane * 32 + i2] = ov[2]; VT[lane * 32 + i3] = ov[3];
    __syncthreads();                      // S2: UT/VT published; le1 readers done
    stage4096(slA, P.lt1w, tid);          // lt1 zc-half  (overlaps pair)
    stage4096(slB, P.lt1w + 4096, tid);   // lt1 agg-half
    pair_mlp(lane, wave, P.le2w, P.le3w, P.le1b, P.le2b, P.le3b);
    __syncthreads();                      // S3: agg done; lt1 visible
    float o1[4] = {lb1, lb1, lb1, lb1};
    dense4L<16>(sBn, sBn + 64, sBn + 128, sBn + 192, slA, 64, lane, o1);  // zc half
    dense4T<16>(AGT, i0, i1, i2, i3, slB, 64, lane, o1);                  // agg half
    sBn[lane] = frelu(o1[0]); sBn[64 + lane] = frelu(o1[1]);
    sBn[128 + lane] = frelu(o1[2]); sBn[192 + lane] = frelu(o1[3]);
    __syncthreads();                      // S4: lt1 readers done
    stage4096(slA, P.lt2w, tid);
    stageN(slB, P.lt3w, 512, tid);
    stageN(slB + 2048, P.lt4w, 128, tid);
    stageN(slB + 2560, P.lt5w, 256, tid);
    __syncthreads();                      // S5: lt2-5 visible
    float o2[4] = {lb2, lb2, lb2, lb2};
    dense4L<16>(sBn, sBn + 64, sBn + 128, sBn + 192, slA, 64, lane, o2);
    sBn[lane] = frelu(o2[0]); sBn[64 + lane] = frelu(o2[1]);
    sBn[128 + lane] = frelu(o2[2]); sBn[192 + lane] = frelu(o2[3]);
    float o3[4] = {lb3, lb3, lb3, lb3};
    dense4L<16>(sBn, sBn + 64, sBn + 128, sBn + 192, slB, 32, cc, o3);
    sBn[cc] = frelu(o3[0]); sBn[64 + cc] = frelu(o3[1]);
    sBn[128 + cc] = frelu(o3[2]); sBn[192 + cc] = frelu(o3[3]);
    float o4[4] = {lb4, lb4, lb4, lb4};
    dense4L<8>(sBn, sBn + 64, sBn + 128, sBn + 192, slB + 2048, 16, c16, o4);
    sBn[c16] = frelu(o4[0]); sBn[64 + c16] = frelu(o4[1]);
    sBn[128 + c16] = frelu(o4[2]); sBn[192 + c16] = frelu(o4[3]);
    float o5[4] = {lb5, lb5, lb5, lb5};
    dense4L<4>(sBn, sBn + 64, sBn + 128, sBn + 192, slB + 2560, 64, lane, o5);
    zci[0] += o5[0]; zci[1] += o5[1]; zci[2] += o5[2]; zci[3] += o5[3];
    if (lane < 32) {
      outb[(t * NO + i0) * NEE + lane] = zci[0];
      outb[(t * NO + i1) * NEE + lane] = zci[1];
      outb[(t * NO + i2) * NEE + lane] = zci[2];
      outb[(t * NO + i3) * NEE + lane] = zci[3];
    }
  }
}

extern "C" void kernel_launch(void* const* d_in, const int* in_sizes, int n_in,
                              void* d_out, int out_size, void* d_ws, size_t ws_size,
                              hipStream_t stream) {
  (void)in_sizes; (void)n_in; (void)d_ws; (void)ws_size;
  Params P;
  int q = 0;
  P.z    = (fp)d_in[q++];
  P.ee1w = (fp)d_in[q++]; P.ee1b = (fp)d_in[q++];
  P.ee2w = (fp)d_in[q++]; P.ee2b = (fp)d_in[q++];
  P.ee3w = (fp)d_in[q++]; P.ee3b = (fp)d_in[q++];
  P.ne1w = (fp)d_in[q++]; P.ne1b = (fp)d_in[q++];
  P.ne2w = (fp)d_in[q++]; P.ne2b = (fp)d_in[q++];
  P.ne3w = (fp)d_in[q++]; P.ne3b = (fp)d_in[q++];
  P.ne4w = (fp)d_in[q++]; P.ne4b = (fp)d_in[q++];
  P.le1w = (fp)d_in[q++]; P.le1b = (fp)d_in[q++];
  P.le2w = (fp)d_in[q++]; P.le2b = (fp)d_in[q++];
  P.le3w = (fp)d_in[q++]; P.le3b = (fp)d_in[q++];
  P.lt1w = (fp)d_in[q++]; P.lt1b = (fp)d_in[q++];
  P.lt2w = (fp)d_in[q++]; P.lt2b = (fp)d_in[q++];
  P.lt3w = (fp)d_in[q++]; P.lt3b = (fp)d_in[q++];
  P.lt4w = (fp)d_in[q++]; P.lt4b = (fp)d_in[q++];
  P.lt5w = (fp)d_in[q++]; P.lt5b = (fp)d_in[q++];
  P.out = (float*)d_out;
  P.tf = out_size / (NB * NO * NEE);
  if (P.tf < 1) P.tf = 1;
  hipLaunchKernelGGL(rld_kernel, dim3(NB), dim3(THREADS), 0, stream, P);
}

// Round 4
// 2284.623 us; speedup vs baseline: 1.0364x; 1.0364x over previous
//
#include <hip/hip_runtime.h>
#include <math.h>

#define NB 256
#define NO 32
#define NEE 32
#define NT 16
#define THREADS 512

typedef const float* __restrict__ fp;

struct Params {
  fp z;
  fp ee1w, ee1b, ee2w, ee2b, ee3w, ee3b;
  fp ne1w, ne1b, ne2w, ne2b, ne3w, ne3b, ne4w, ne4b;
  fp le1w, le1b, le2w, le2b, le3w, le3b;
  fp lt1w, lt1b, lt2w, lt2b, lt3w, lt3b, lt4w, lt4b, lt5w, lt5b;
  float* out;
  int tf;
};

__device__ __forceinline__ float frelu(float x) { return x > 0.f ? x : 0.f; }

// LDS float offsets (14592 floats = 57 KiB static)
#define OFF_UT  0       // [64][33] u transposed (h-major), padded: bank = (h+i)%32
#define OFF_VT  2112    // [64][33] v transposed
#define OFF_AG0 4224    // [64][33] agg buf 0 (c-major)
#define OFF_AG1 6336    // [64][33] agg buf 1
#define OFF_BN  8448    // 8 waves x 256 wave-private bounce
#define OFF_SRC 10496   // [32][128] A1 source chunk
#define LDSF    14592

__device__ __forceinline__ float* get_lds() {
  __shared__ float L[LDSF];
  return L;
}

// 4-row dense; w may be GLOBAL (L2-resident, coalesced) or LDS; x rows are
// LDS broadcast float4 reads. One w read serves 4 rows.
template<int KC>
__device__ __forceinline__ void dense4L(const float* x0, const float* x1,
                                        const float* x2, const float* x3,
                                        const float* __restrict__ w, int ldw,
                                        int col, float o[4]) {
#pragma unroll 4
  for (int kc = 0; kc < KC; ++kc) {
    float w0 = w[(4 * kc + 0) * ldw + col];
    float w1 = w[(4 * kc + 1) * ldw + col];
    float w2 = w[(4 * kc + 2) * ldw + col];
    float w3 = w[(4 * kc + 3) * ldw + col];
    float4 a = *(const float4*)(x0 + 4 * kc);
    float4 b = *(const float4*)(x1 + 4 * kc);
    float4 c = *(const float4*)(x2 + 4 * kc);
    float4 d = *(const float4*)(x3 + 4 * kc);
    o[0] = fmaf(a.x, w0, o[0]); o[0] = fmaf(a.y, w1, o[0]); o[0] = fmaf(a.z, w2, o[0]); o[0] = fmaf(a.w, w3, o[0]);
    o[1] = fmaf(b.x, w0, o[1]); o[1] = fmaf(b.y, w1, o[1]); o[1] = fmaf(b.z, w2, o[1]); o[1] = fmaf(b.w, w3, o[1]);
    o[2] = fmaf(c.x, w0, o[2]); o[2] = fmaf(c.y, w1, o[2]); o[2] = fmaf(c.z, w2, o[2]); o[2] = fmaf(c.w, w3, o[2]);
    o[3] = fmaf(d.x, w0, o[3]); o[3] = fmaf(d.y, w1, o[3]); o[3] = fmaf(d.z, w2, o[3]); o[3] = fmaf(d.w, w3, o[3]);
  }
}

// Same, x from TRANSPOSED padded [k][33] LDS buffer (uniform broadcast reads).
template<int KC>
__device__ __forceinline__ void dense4T(const float* xt, int r0, int r1, int r2, int r3,
                                        const float* __restrict__ w, int ldw,
                                        int col, float o[4]) {
#pragma unroll 4
  for (int kc = 0; kc < KC; ++kc) {
#pragma unroll
    for (int jj = 0; jj < 4; ++jj) {
      int k = 4 * kc + jj;
      float wk = w[k * ldw + col];
      o[0] = fmaf(xt[k * 33 + r0], wk, o[0]);
      o[1] = fmaf(xt[k * 33 + r1], wk, o[1]);
      o[2] = fmaf(xt[k * 33 + r2], wk, o[2]);
      o[3] = fmaf(xt[k * 33 + r3], wk, o[3]);
    }
  }
}

// Pair MLP, lane = one pair (512 slots, 496 real). Weights/biases are
// wave-uniform -> scalar (SMEM) streams; x recomputed from padded UT/VT
// (conflict-free b32 gathers); layer 3 in two c-halves to cap live VGPRs
// (~110: acc[64] + e[32] + misc). noinline: one code copy for A and B.
__device__ __noinline__ void pair_mlp(fp w2, fp w3, fp b1, fp b2, fp b3, int agoff) {
  float* lds = get_lds();
  const int tid = (int)threadIdx.x;
  const int lane = tid & 63;
  const int wave = tid >> 6;
  float* AGT = lds + agoff;

  int p = wave + 8 * lane;              // strided pair assignment
  bool real = (p < 496);
  int pc = real ? p : 0;
  float dd = (float)(3969 - 8 * pc);    // (63-2i)^2 at row boundaries (exact)
  int i = (int)((63.0f - sqrtf(dd)) * 0.5f);
  int off = i * (63 - i) / 2;
  if (pc < off) { --i; off = i * (63 - i) / 2; }
  else { int off2 = (i + 1) * (62 - i) / 2; if (pc >= off2) { ++i; off = off2; } }
  int j = pc - off + i + 1;
  const float* Ui = lds + OFF_UT + i;
  const float* Vj = lds + OFF_VT + j;

  float acc[64];
#pragma unroll
  for (int c = 0; c < 64; ++c) acc[c] = b2[c];
#pragma unroll 4
  for (int h = 0; h < 64; ++h) {
    float x = fmaxf(Ui[h * 33] + Vj[h * 33] + b1[h], 0.f);
    const float* wr = w2 + h * 64;
#pragma unroll
    for (int c = 0; c < 64; ++c) acc[c] = fmaf(x, wr[c], acc[c]);
  }
#pragma unroll
  for (int half = 0; half < 2; ++half) {
    float e[32];
#pragma unroll
    for (int c = 0; c < 32; ++c) e[c] = b3[half * 32 + c];
#pragma unroll
    for (int h = 0; h < 64; ++h) {     // full unroll: acc[h] must stay static
      float x = fmaxf(acc[h], 0.f);
      const float* wr = w3 + h * 64 + half * 32;
#pragma unroll
      for (int c = 0; c < 32; ++c) e[c] = fmaf(x, wr[c], e[c]);
    }
    if (real) {
#pragma unroll
      for (int c = 0; c < 32; ++c) {
        atomicAdd(&AGT[(half * 32 + c) * 33 + i],  e[c]);
        atomicAdd(&AGT[(half * 32 + c) * 33 + j], -e[c]);
      }
    }
  }
}

__global__ __launch_bounds__(THREADS, 2) void rld_kernel(Params P) {
  float* lds = get_lds();
  const int b = blockIdx.x;
  const int tid = (int)threadIdx.x;
  const int lane = tid & 63;
  const int wave = tid >> 6;
  const int cc = lane & 31;
  const int c16 = lane & 15;

  float* UT = lds + OFF_UT;
  float* VT = lds + OFF_VT;
  float* sBn = lds + OFF_BN + wave * 256;   // wave-private bounce
  float* src = lds + OFF_SRC;
  const int i0 = wave, i1 = wave + 8, i2 = wave + 16, i3 = wave + 24;
  const float* zb = P.z + (size_t)b * NT * NO * NEE;

  // ===== A1: src[32,512] @ {ee1a, ee1b, ne1a}; weights global-direct =====
  float au[4] = {0,0,0,0}, av[4] = {0,0,0,0}, s1r[4] = {0,0,0,0};
  for (int qq = 0; qq < 4; ++qq) {
    __syncthreads();                    // prior chunk readers done
    for (int idx = tid; idx < 4096; idx += THREADS) {
      int i = idx >> 7, kk = idx & 127;
      int k = qq * 128 + kk, t = k >> 5, e = k & 31;
      float v = zb[(t * NO + i) * NEE + e];
      if (t > 0) v -= zb[((t - 1) * NO + i) * NEE + e];
      src[i * 128 + kk] = v;
    }
    __syncthreads();                    // chunk visible
    for (int c = 0; c < 4; ++c) {
      int r0 = qq * 128 + c * 32;
      const float* x0 = src + i0 * 128 + c * 32;
      const float* x1 = src + i1 * 128 + c * 32;
      const float* x2 = src + i2 * 128 + c * 32;
      const float* x3 = src + i3 * 128 + c * 32;
      dense4L<8>(x0, x1, x2, x3, P.ee1w + (size_t)r0 * 64,        64, lane, au);
      dense4L<8>(x0, x1, x2, x3, P.ee1w + (size_t)(512 + r0) * 64, 64, lane, av);
      dense4L<8>(x0, x1, x2, x3, P.ne1w + (size_t)r0 * 64,        64, lane, s1r);
    }
  }
  // publish u/v transposed+padded; zero AG0
  UT[lane * 33 + i0] = au[0]; UT[lane * 33 + i1] = au[1];
  UT[lane * 33 + i2] = au[2]; UT[lane * 33 + i3] = au[3];
  VT[lane * 33 + i0] = av[0]; VT[lane * 33 + i1] = av[1];
  VT[lane * 33 + i2] = av[2]; VT[lane * 33 + i3] = av[3];
  for (int z = tid; z < 2112; z += THREADS) lds[OFF_AG0 + z] = 0.f;
  __syncthreads();

  // ===== A2: ee edge MLP =====
  pair_mlp(P.ee2w, P.ee3w, P.ee1b, P.ee2b, P.ee3b, OFF_AG0);
  __syncthreads();

  // ===== A3: ne node MLP -> zci[4]; weights global-direct =====
  float zci[4];
  {
    float nb1 = P.ne1b[lane], nb2 = P.ne2b[lane];
    float nb3 = P.ne3b[cc],   nb4 = P.ne4b[cc];
    float o1[4] = {s1r[0] + nb1, s1r[1] + nb1, s1r[2] + nb1, s1r[3] + nb1};
    dense4T<16>(lds + OFF_AG0, i0, i1, i2, i3, P.ne1w + (size_t)512 * 64, 64, lane, o1);
    sBn[lane] = frelu(o1[0]); sBn[64 + lane] = frelu(o1[1]);
    sBn[128 + lane] = frelu(o1[2]); sBn[192 + lane] = frelu(o1[3]);
    float o2[4] = {nb2, nb2, nb2, nb2};
    dense4L<16>(sBn, sBn + 64, sBn + 128, sBn + 192, P.ne2w, 64, lane, o2);
    sBn[lane] = frelu(o2[0]); sBn[64 + lane] = frelu(o2[1]);
    sBn[128 + lane] = frelu(o2[2]); sBn[192 + lane] = frelu(o2[3]);
    float o3[4] = {nb3, nb3, nb3, nb3};
    dense4L<16>(sBn, sBn + 64, sBn + 128, sBn + 192, P.ne3w, 32, cc, o3);
    sBn[cc] = frelu(o3[0]); sBn[64 + cc] = frelu(o3[1]);
    sBn[128 + cc] = frelu(o3[2]); sBn[192 + cc] = frelu(o3[3]);
    float o4[4] = {nb4, nb4, nb4, nb4};
    dense4L<8>(sBn, sBn + 64, sBn + 128, sBn + 192, P.ne4w, 32, cc, o4);
    zci[0] = (lane < 32) ? zb[(15 * NO + i0) * NEE + lane] : o4[0];
    zci[1] = (lane < 32) ? zb[(15 * NO + i1) * NEE + lane] : o4[1];
    zci[2] = (lane < 32) ? zb[(15 * NO + i2) * NEE + lane] : o4[2];
    zci[3] = (lane < 32) ? zb[(15 * NO + i3) * NEE + lane] : o4[3];
  }

  float lb1 = P.lt1b[lane], lb2 = P.lt2b[lane];
  float lb3 = P.lt3b[cc],   lb4 = P.lt4b[c16], lb5 = P.lt5b[lane];
  float* outb = P.out + (size_t)b * P.tf * NO * NEE;

  // ===== Phase B: 2 barriers/step; agg double-buffered by t-parity =====
  // (t even uses AG1, so A3's AG0 reads race nothing at t=0)
  for (int t = 0; t < P.tf; ++t) {
    const int ago = (t & 1) ? OFF_AG0 : OFF_AG1;
    sBn[lane] = zci[0]; sBn[64 + lane] = zci[1];
    sBn[128 + lane] = zci[2]; sBn[192 + lane] = zci[3];
    float ou[4] = {0,0,0,0}, ov[4] = {0,0,0,0};
    dense4L<16>(sBn, sBn + 64, sBn + 128, sBn + 192, P.le1w,        64, lane, ou);
    dense4L<16>(sBn, sBn + 64, sBn + 128, sBn + 192, P.le1w + 4096, 64, lane, ov);
    UT[lane * 33 + i0] = ou[0]; UT[lane * 33 + i1] = ou[1];
    UT[lane * 33 + i2] = ou[2]; UT[lane * 33 + i3] = ou[3];
    VT[lane * 33 + i0] = ov[0]; VT[lane * 33 + i1] = ov[1];
    VT[lane * 33 + i2] = ov[2]; VT[lane * 33 + i3] = ov[3];
    for (int z = tid; z < 2112; z += THREADS) lds[ago + z] = 0.f;
    __syncthreads();                    // B1: u/v + agg-zero published
    pair_mlp(P.le2w, P.le3w, P.le1b, P.le2b, P.le3b, ago);
    __syncthreads();                    // B2: agg complete
    float o1[4] = {lb1, lb1, lb1, lb1};
    dense4L<16>(sBn, sBn + 64, sBn + 128, sBn + 192, P.lt1w, 64, lane, o1);   // zc half
    dense4T<16>(lds + ago, i0, i1, i2, i3, P.lt1w + (size_t)64 * 64, 64, lane, o1); // agg half
    sBn[lane] = frelu(o1[0]); sBn[64 + lane] = frelu(o1[1]);
    sBn[128 + lane] = frelu(o1[2]); sBn[192 + lane] = frelu(o1[3]);
    float o2[4] = {lb2, lb2, lb2, lb2};
    dense4L<16>(sBn, sBn + 64, sBn + 128, sBn + 192, P.lt2w, 64, lane, o2);
    sBn[lane] = frelu(o2[0]); sBn[64 + lane] = frelu(o2[1]);
    sBn[128 + lane] = frelu(o2[2]); sBn[192 + lane] = frelu(o2[3]);
    float o3[4] = {lb3, lb3, lb3, lb3};
    dense4L<16>(sBn, sBn + 64, sBn + 128, sBn + 192, P.lt3w, 32, cc, o3);
    sBn[cc] = frelu(o3[0]); sBn[64 + cc] = frelu(o3[1]);
    sBn[128 + cc] = frelu(o3[2]); sBn[192 + cc] = frelu(o3[3]);
    float o4[4] = {lb4, lb4, lb4, lb4};
    dense4L<8>(sBn, sBn + 64, sBn + 128, sBn + 192, P.lt4w, 16, c16, o4);
    sBn[c16] = frelu(o4[0]); sBn[64 + c16] = frelu(o4[1]);
    sBn[128 + c16] = frelu(o4[2]); sBn[192 + c16] = frelu(o4[3]);
    float o5[4] = {lb5, lb5, lb5, lb5};
    dense4L<4>(sBn, sBn + 64, sBn + 128, sBn + 192, P.lt5w, 64, lane, o5);
    zci[0] += o5[0]; zci[1] += o5[1]; zci[2] += o5[2]; zci[3] += o5[3];
    if (lane < 32) {
      outb[(t * NO + i0) * NEE + lane] = zci[0];
      outb[(t * NO + i1) * NEE + lane] = zci[1];
      outb[(t * NO + i2) * NEE + lane] = zci[2];
      outb[(t * NO + i3) * NEE + lane] = zci[3];
    }
  }
}

extern "C" void kernel_launch(void* const* d_in, const int* in_sizes, int n_in,
                              void* d_out, int out_size, void* d_ws, size_t ws_size,
                              hipStream_t stream) {
  (void)in_sizes; (void)n_in; (void)d_ws; (void)ws_size;
  Params P;
  int q = 0;
  P.z    = (fp)d_in[q++];
  P.ee1w = (fp)d_in[q++]; P.ee1b = (fp)d_in[q++];
  P.ee2w = (fp)d_in[q++]; P.ee2b = (fp)d_in[q++];
  P.ee3w = (fp)d_in[q++]; P.ee3b = (fp)d_in[q++];
  P.ne1w = (fp)d_in[q++]; P.ne1b = (fp)d_in[q++];
  P.ne2w = (fp)d_in[q++]; P.ne2b = (fp)d_in[q++];
  P.ne3w = (fp)d_in[q++]; P.ne3b = (fp)d_in[q++];
  P.ne4w = (fp)d_in[q++]; P.ne4b = (fp)d_in[q++];
  P.le1w = (fp)d_in[q++]; P.le1b = (fp)d_in[q++];
  P.le2w = (fp)d_in[q++]; P.le2b = (fp)d_in[q++];
  P.le3w = (fp)d_in[q++]; P.le3b = (fp)d_in[q++];
  P.lt1w = (fp)d_in[q++]; P.lt1b = (fp)d_in[q++];
  P.lt2w = (fp)d_in[q++]; P.lt2b = (fp)d_in[q++];
  P.lt3w = (fp)d_in[q++]; P.lt3b = (fp)d_in[q++];
  P.lt4w = (fp)d_in[q++]; P.lt4b = (fp)d_in[q++];
  P.lt5w = (fp)d_in[q++]; P.lt5b = (fp)d_in[q++];
  P.out = (float*)d_out;
  P.tf = out_size / (NB * NO * NEE);
  if (P.tf < 1) P.tf = 1;
  hipLaunchKernelGGL(rld_kernel, dim3(NB), dim3(THREADS), 0, stream, P);
}

// Round 5
// 1874.748 us; speedup vs baseline: 1.2630x; 1.2186x over previous
//
#include <hip/hip_runtime.h>
#include <math.h>

#define NB 256
#define NO 32
#define NEE 32
#define NT 16
#define THREADS 512

typedef const float* __restrict__ fp;

struct Params {
  fp z;
  fp ee1w, ee1b, ee2w, ee2b, ee3w, ee3b;
  fp ne1w, ne1b, ne2w, ne2b, ne3w, ne3b, ne4w, ne4b;
  fp le1w, le1b, le2w, le2b, le3w, le3b;
  fp lt1w, lt1b, lt2w, lt2b, lt3w, lt3b, lt4w, lt4b, lt5w, lt5b;
  float* out;
  int tf;
};

__device__ __forceinline__ float frelu(float x) { return x > 0.f ? x : 0.f; }

// LDS float offsets (14592 floats = 57 KiB static)
#define OFF_UT  0       // [64][33] u transposed (h-major), padded: bank=(h+i)%32
#define OFF_VT  2112    // [64][33] v transposed
#define OFF_AG0 4224    // [64][33] agg buf 0 (c-major)
#define OFF_AG1 6336    // [64][33] agg buf 1
#define OFF_BN  8448    // 8 waves x 256 wave-private bounce
#define OFF_SRC 10496   // [32][128] A1 source chunk
#define LDSF    14592

// 4-row dense; w GLOBAL (L2-resident, coalesced per-lane col) or LDS;
// x rows are LDS broadcast float4 reads. One w read serves 4 rows.
template<int KC>
__device__ __forceinline__ void dense4L(const float* x0, const float* x1,
                                        const float* x2, const float* x3,
                                        const float* __restrict__ w, int ldw,
                                        int col, float o[4]) {
#pragma unroll 4
  for (int kc = 0; kc < KC; ++kc) {
    float w0 = w[(4 * kc + 0) * ldw + col];
    float w1 = w[(4 * kc + 1) * ldw + col];
    float w2 = w[(4 * kc + 2) * ldw + col];
    float w3 = w[(4 * kc + 3) * ldw + col];
    float4 a = *(const float4*)(x0 + 4 * kc);
    float4 b = *(const float4*)(x1 + 4 * kc);
    float4 c = *(const float4*)(x2 + 4 * kc);
    float4 d = *(const float4*)(x3 + 4 * kc);
    o[0] = fmaf(a.x, w0, o[0]); o[0] = fmaf(a.y, w1, o[0]); o[0] = fmaf(a.z, w2, o[0]); o[0] = fmaf(a.w, w3, o[0]);
    o[1] = fmaf(b.x, w0, o[1]); o[1] = fmaf(b.y, w1, o[1]); o[1] = fmaf(b.z, w2, o[1]); o[1] = fmaf(b.w, w3, o[1]);
    o[2] = fmaf(c.x, w0, o[2]); o[2] = fmaf(c.y, w1, o[2]); o[2] = fmaf(c.z, w2, o[2]); o[2] = fmaf(c.w, w3, o[2]);
    o[3] = fmaf(d.x, w0, o[3]); o[3] = fmaf(d.y, w1, o[3]); o[3] = fmaf(d.z, w2, o[3]); o[3] = fmaf(d.w, w3, o[3]);
  }
}

// Same, x from TRANSPOSED padded [k][33] LDS buffer (per-lane gathers).
template<int KC>
__device__ __forceinline__ void dense4T(const float* xt, int r0, int r1, int r2, int r3,
                                        const float* __restrict__ w, int ldw,
                                        int col, float o[4]) {
#pragma unroll 4
  for (int kc = 0; kc < KC; ++kc) {
#pragma unroll
    for (int jj = 0; jj < 4; ++jj) {
      int k = 4 * kc + jj;
      float wk = w[k * ldw + col];
      o[0] = fmaf(xt[k * 33 + r0], wk, o[0]);
      o[1] = fmaf(xt[k * 33 + r1], wk, o[1]);
      o[2] = fmaf(xt[k * 33 + r2], wk, o[2]);
      o[3] = fmaf(xt[k * 33 + r3], wk, o[3]);
    }
  }
}

// Pair MLP, lane = one pair (512 slots, 496 real). Fully inlined; weight
// pointers uniform -> scalar weight streams. Layer 3 in QUARTERS (e[16])
// to cap live VGPRs (~100 peak: acc[64]+e[16]+misc).
__device__ __forceinline__ void pair_block(float* lds, fp w2, fp w3,
                                           fp b1, fp b2, fp b3, int agoff) {
  const int tid = (int)threadIdx.x;
  const int lane = tid & 63;
  const int wave = tid >> 6;
  float* AGT = lds + agoff;

  int p = wave + 8 * lane;              // strided pair assignment
  bool real = (p < 496);
  int pc = real ? p : 0;
  float dd = (float)(3969 - 8 * pc);    // (63-2i)^2 at row boundaries (exact)
  int i = (int)((63.0f - sqrtf(dd)) * 0.5f);
  int off = i * (63 - i) / 2;
  if (pc < off) { --i; off = i * (63 - i) / 2; }
  else { int off2 = (i + 1) * (62 - i) / 2; if (pc >= off2) { ++i; off = off2; } }
  int j = pc - off + i + 1;
  const float* Ui = lds + OFF_UT + i;
  const float* Vj = lds + OFF_VT + j;

  float acc[64];
#pragma unroll
  for (int c = 0; c < 64; ++c) acc[c] = b2[c];
#pragma unroll 2
  for (int h = 0; h < 64; ++h) {        // rolled: bounds load-hoisting scope
    float x = fmaxf(Ui[h * 33] + Vj[h * 33] + b1[h], 0.f);
    const float* wr = w2 + h * 64;
#pragma unroll
    for (int c = 0; c < 64; ++c) acc[c] = fmaf(x, wr[c], acc[c]);
  }
#pragma unroll
  for (int h = 0; h < 64; ++h) acc[h] = fmaxf(acc[h], 0.f);
#pragma unroll
  for (int quar = 0; quar < 4; ++quar) {
    float e[16];
#pragma unroll
    for (int c = 0; c < 16; ++c) e[c] = b3[quar * 16 + c];
#pragma unroll
    for (int h = 0; h < 64; ++h) {      // static acc[h]
      const float* wr = w3 + h * 64 + quar * 16;
#pragma unroll
      for (int c = 0; c < 16; ++c) e[c] = fmaf(acc[h], wr[c], e[c]);
    }
    if (real) {
#pragma unroll
      for (int c = 0; c < 16; ++c) {
        atomicAdd(&AGT[(quar * 16 + c) * 33 + i],  e[c]);
        atomicAdd(&AGT[(quar * 16 + c) * 33 + j], -e[c]);
      }
    }
  }
}

__global__ __launch_bounds__(THREADS) void rld_kernel(Params P) {
  __shared__ float lds[LDSF];
  const int b = blockIdx.x;
  const int tid = (int)threadIdx.x;
  const int lane = tid & 63;
  const int wave = tid >> 6;
  const int cc = lane & 31;
  const int c16 = lane & 15;

  float* UT = lds + OFF_UT;
  float* VT = lds + OFF_VT;
  float* sBn = lds + OFF_BN + wave * 256;   // wave-private bounce
  float* src = lds + OFF_SRC;
  const int i0 = wave, i1 = wave + 8, i2 = wave + 16, i3 = wave + 24;
  const float* zb = P.z + (size_t)b * NT * NO * NEE;

  // ===== A1: src[32,512] @ {ee1a, ee1b, ne1a}; weights global-direct =====
  float au[4] = {0,0,0,0}, av[4] = {0,0,0,0}, s1r[4] = {0,0,0,0};
  for (int qq = 0; qq < 4; ++qq) {
    __syncthreads();                    // prior chunk readers done
    for (int idx = tid; idx < 4096; idx += THREADS) {
      int i = idx >> 7, kk = idx & 127;
      int k = qq * 128 + kk, t = k >> 5, e = k & 31;
      float v = zb[(t * NO + i) * NEE + e];
      if (t > 0) v -= zb[((t - 1) * NO + i) * NEE + e];
      src[i * 128 + kk] = v;
    }
    __syncthreads();                    // chunk visible
    for (int c = 0; c < 4; ++c) {
      int r0 = qq * 128 + c * 32;
      const float* x0 = src + i0 * 128 + c * 32;
      const float* x1 = src + i1 * 128 + c * 32;
      const float* x2 = src + i2 * 128 + c * 32;
      const float* x3 = src + i3 * 128 + c * 32;
      dense4L<8>(x0, x1, x2, x3, P.ee1w + (size_t)r0 * 64,         64, lane, au);
      dense4L<8>(x0, x1, x2, x3, P.ee1w + (size_t)(512 + r0) * 64, 64, lane, av);
      dense4L<8>(x0, x1, x2, x3, P.ne1w + (size_t)r0 * 64,         64, lane, s1r);
    }
  }
  // publish u/v transposed+padded; zero AG0
  UT[lane * 33 + i0] = au[0]; UT[lane * 33 + i1] = au[1];
  UT[lane * 33 + i2] = au[2]; UT[lane * 33 + i3] = au[3];
  VT[lane * 33 + i0] = av[0]; VT[lane * 33 + i1] = av[1];
  VT[lane * 33 + i2] = av[2]; VT[lane * 33 + i3] = av[3];
  for (int z = tid; z < 2112; z += THREADS) lds[OFF_AG0 + z] = 0.f;
  __syncthreads();

  const int tf = P.tf;
  float zci[4] = {0, 0, 0, 0};
  float* outb = P.out + (size_t)b * tf * NO * NEE;

  // ===== merged loop: s=0 -> ee pair + ne node; s>=1 -> le pair + lt node =====
  for (int s = 0; s <= tf; ++s) {
    fp w2p = s ? P.le2w : P.ee2w;
    fp w3p = s ? P.le3w : P.ee3w;
    fp b1p = s ? P.le1b : P.ee1b;
    fp b2p = s ? P.le2b : P.ee2b;
    fp b3p = s ? P.le3b : P.ee3b;
    const int ago = (s & 1) ? OFF_AG1 : OFF_AG0;

    pair_block(lds, w2p, w3p, b1p, b2p, b3p, ago);
    __syncthreads();                    // agg complete

    if (s == 0) {
      // ----- A3: ne node MLP -> zci -----
      float nb1 = P.ne1b[lane], nb2 = P.ne2b[lane];
      float nb3 = P.ne3b[cc],   nb4 = P.ne4b[cc];
      float o1[4] = {s1r[0] + nb1, s1r[1] + nb1, s1r[2] + nb1, s1r[3] + nb1};
      dense4T<16>(lds + ago, i0, i1, i2, i3, P.ne1w + (size_t)512 * 64, 64, lane, o1);
      sBn[lane] = frelu(o1[0]); sBn[64 + lane] = frelu(o1[1]);
      sBn[128 + lane] = frelu(o1[2]); sBn[192 + lane] = frelu(o1[3]);
      float o2[4] = {nb2, nb2, nb2, nb2};
      dense4L<16>(sBn, sBn + 64, sBn + 128, sBn + 192, P.ne2w, 64, lane, o2);
      sBn[lane] = frelu(o2[0]); sBn[64 + lane] = frelu(o2[1]);
      sBn[128 + lane] = frelu(o2[2]); sBn[192 + lane] = frelu(o2[3]);
      float o3[4] = {nb3, nb3, nb3, nb3};
      dense4L<16>(sBn, sBn + 64, sBn + 128, sBn + 192, P.ne3w, 32, cc, o3);
      sBn[cc] = frelu(o3[0]); sBn[64 + cc] = frelu(o3[1]);
      sBn[128 + cc] = frelu(o3[2]); sBn[192 + cc] = frelu(o3[3]);
      float o4[4] = {nb4, nb4, nb4, nb4};
      dense4L<8>(sBn, sBn + 64, sBn + 128, sBn + 192, P.ne4w, 32, cc, o4);
      zci[0] = (lane < 32) ? zb[(15 * NO + i0) * NEE + lane] : o4[0];
      zci[1] = (lane < 32) ? zb[(15 * NO + i1) * NEE + lane] : o4[1];
      zci[2] = (lane < 32) ? zb[(15 * NO + i2) * NEE + lane] : o4[2];
      zci[3] = (lane < 32) ? zb[(15 * NO + i3) * NEE + lane] : o4[3];
    } else {
      // ----- lt node MLP; sBn still holds zci bounce from prep(s-1) -----
      float lb1 = P.lt1b[lane], lb2 = P.lt2b[lane];
      float lb3 = P.lt3b[cc],   lb4 = P.lt4b[c16], lb5 = P.lt5b[lane];
      float o1[4] = {lb1, lb1, lb1, lb1};
      dense4L<16>(sBn, sBn + 64, sBn + 128, sBn + 192, P.lt1w, 64, lane, o1);  // zc half
      dense4T<16>(lds + ago, i0, i1, i2, i3, P.lt1w + (size_t)64 * 64, 64, lane, o1); // agg half
      sBn[lane] = frelu(o1[0]); sBn[64 + lane] = frelu(o1[1]);
      sBn[128 + lane] = frelu(o1[2]); sBn[192 + lane] = frelu(o1[3]);
      float o2[4] = {lb2, lb2, lb2, lb2};
      dense4L<16>(sBn, sBn + 64, sBn + 128, sBn + 192, P.lt2w, 64, lane, o2);
      sBn[lane] = frelu(o2[0]); sBn[64 + lane] = frelu(o2[1]);
      sBn[128 + lane] = frelu(o2[2]); sBn[192 + lane] = frelu(o2[3]);
      float o3[4] = {lb3, lb3, lb3, lb3};
      dense4L<16>(sBn, sBn + 64, sBn + 128, sBn + 192, P.lt3w, 32, cc, o3);
      sBn[cc] = frelu(o3[0]); sBn[64 + cc] = frelu(o3[1]);
      sBn[128 + cc] = frelu(o3[2]); sBn[192 + cc] = frelu(o3[3]);
      float o4[4] = {lb4, lb4, lb4, lb4};
      dense4L<8>(sBn, sBn + 64, sBn + 128, sBn + 192, P.lt4w, 16, c16, o4);
      sBn[c16] = frelu(o4[0]); sBn[64 + c16] = frelu(o4[1]);
      sBn[128 + c16] = frelu(o4[2]); sBn[192 + c16] = frelu(o4[3]);
      float o5[4] = {lb5, lb5, lb5, lb5};
      dense4L<4>(sBn, sBn + 64, sBn + 128, sBn + 192, P.lt5w, 64, lane, o5);
      zci[0] += o5[0]; zci[1] += o5[1]; zci[2] += o5[2]; zci[3] += o5[3];
      int t = s - 1;
      if (lane < 32) {
        outb[(t * NO + i0) * NEE + lane] = zci[0];
        outb[(t * NO + i1) * NEE + lane] = zci[1];
        outb[(t * NO + i2) * NEE + lane] = zci[2];
        outb[(t * NO + i3) * NEE + lane] = zci[3];
      }
    }

    if (s < tf) {
      // ----- prep next step: zc bounce, le1 -> UT/VT, zero other AG -----
      sBn[lane] = zci[0]; sBn[64 + lane] = zci[1];
      sBn[128 + lane] = zci[2]; sBn[192 + lane] = zci[3];
      float ou[4] = {0,0,0,0}, ov[4] = {0,0,0,0};
      dense4L<16>(sBn, sBn + 64, sBn + 128, sBn + 192, P.le1w,        64, lane, ou);
      dense4L<16>(sBn, sBn + 64, sBn + 128, sBn + 192, P.le1w + 4096, 64, lane, ov);
      UT[lane * 33 + i0] = ou[0]; UT[lane * 33 + i1] = ou[1];
      UT[lane * 33 + i2] = ou[2]; UT[lane * 33 + i3] = ou[3];
      VT[lane * 33 + i0] = ov[0]; VT[lane * 33 + i1] = ov[1];
      VT[lane * 33 + i2] = ov[2]; VT[lane * 33 + i3] = ov[3];
      const int agn = ((s + 1) & 1) ? OFF_AG1 : OFF_AG0;
      for (int z = tid; z < 2112; z += THREADS) lds[agn + z] = 0.f;
    }
    __syncthreads();                    // UT/VT + agg-zero published
  }
}

extern "C" void kernel_launch(void* const* d_in, const int* in_sizes, int n_in,
                              void* d_out, int out_size, void* d_ws, size_t ws_size,
                              hipStream_t stream) {
  (void)in_sizes; (void)n_in; (void)d_ws; (void)ws_size;
  Params P;
  int q = 0;
  P.z    = (fp)d_in[q++];
  P.ee1w = (fp)d_in[q++]; P.ee1b = (fp)d_in[q++];
  P.ee2w = (fp)d_in[q++]; P.ee2b = (fp)d_in[q++];
  P.ee3w = (fp)d_in[q++]; P.ee3b = (fp)d_in[q++];
  P.ne1w = (fp)d_in[q++]; P.ne1b = (fp)d_in[q++];
  P.ne2w = (fp)d_in[q++]; P.ne2b = (fp)d_in[q++];
  P.ne3w = (fp)d_in[q++]; P.ne3b = (fp)d_in[q++];
  P.ne4w = (fp)d_in[q++]; P.ne4b = (fp)d_in[q++];
  P.le1w = (fp)d_in[q++]; P.le1b = (fp)d_in[q++];
  P.le2w = (fp)d_in[q++]; P.le2b = (fp)d_in[q++];
  P.le3w = (fp)d_in[q++]; P.le3b = (fp)d_in[q++];
  P.lt1w = (fp)d_in[q++]; P.lt1b = (fp)d_in[q++];
  P.lt2w = (fp)d_in[q++]; P.lt2b = (fp)d_in[q++];
  P.lt3w = (fp)d_in[q++]; P.lt3b = (fp)d_in[q++];
  P.lt4w = (fp)d_in[q++]; P.lt4b = (fp)d_in[q++];
  P.lt5w = (fp)d_in[q++]; P.lt5b = (fp)d_in[q++];
  P.out = (float*)d_out;
  P.tf = out_size / (NB * NO * NEE);
  if (P.tf < 1) P.tf = 1;
  hipLaunchKernelGGL(rld_kernel, dim3(NB), dim3(THREADS), 0, stream, P);
}

// Round 7
// 1178.635 us; speedup vs baseline: 2.0090x; 1.5906x over previous
//
#include <hip/hip_runtime.h>

#define NB 256
#define NO 32
#define NEE 32
#define NT 16
#define THREADS 512

typedef const float* __restrict__ fp;

struct Params {
  fp z;
  fp ee1w, ee1b, ee2w, ee2b, ee3w, ee3b;
  fp ne1w, ne1b, ne2w, ne2b, ne3w, ne3b, ne4w, ne4b;
  fp le1w, le1b, le2w, le2b, le3w, le3b;
  fp lt1w, lt1b, lt2w, lt2b, lt3w, lt3b, lt4w, lt4b, lt5w, lt5b;
  float* out;
  int tf;
};

__device__ __forceinline__ float frelu(float x) { return x > 0.f ? x : 0.f; }

// register-file broadcast: value of lane l (compile-time l after unroll)
__device__ __forceinline__ float rl(float v, int l) {
  return __uint_as_float(__builtin_amdgcn_readlane(__float_as_uint(v), l));
}

// LDS float offsets (16000 floats = 62.5 KiB static)
#define OFF_UT  0       // [64][33] u^T (+b1 folded), bank=(h+i)%32 conflict-free
#define OFF_VT  2112    // [64][33] v^T
#define OFF_AG  4224    // [32][64] agg row-major: atomics bank=lane%32 (2-way free)
#define OFF_BN  6272    // 2048: 8 waves x 256 bounce; doubles as A1 src [32][64]
#define OFF_NW  8320    // 7680: lt2(4096) lt3(2048) lt4(512) lt5(1024), resident
#define LDSF    16000

__device__ __forceinline__ void stageN(float* dst, const float* __restrict__ src,
                                       int nf4, int tid) {
  for (int i4 = tid; i4 < nf4; i4 += THREADS)
    *(float4*)(dst + i4 * 4) = *(const float4*)(src + i4 * 4);
}

// 4-row dense; w from GLOBAL (coalesced per-lane col) or LDS (b32, conflict-free);
// x rows are LDS float4 broadcasts. One w read serves 4 rows.
template<int KC>
__device__ __forceinline__ void dense4L(const float* x0, const float* x1,
                                        const float* x2, const float* x3,
                                        const float* __restrict__ w, int ldw,
                                        int col, float o[4]) {
#pragma unroll 4
  for (int kc = 0; kc < KC; ++kc) {
    float w0 = w[(4 * kc + 0) * ldw + col];
    float w1 = w[(4 * kc + 1) * ldw + col];
    float w2 = w[(4 * kc + 2) * ldw + col];
    float w3 = w[(4 * kc + 3) * ldw + col];
    float4 a = *(const float4*)(x0 + 4 * kc);
    float4 b = *(const float4*)(x1 + 4 * kc);
    float4 c = *(const float4*)(x2 + 4 * kc);
    float4 d = *(const float4*)(x3 + 4 * kc);
    o[0] = fmaf(a.x, w0, o[0]); o[0] = fmaf(a.y, w1, o[0]); o[0] = fmaf(a.z, w2, o[0]); o[0] = fmaf(a.w, w3, o[0]);
    o[1] = fmaf(b.x, w0, o[1]); o[1] = fmaf(b.y, w1, o[1]); o[1] = fmaf(b.z, w2, o[1]); o[1] = fmaf(b.w, w3, o[1]);
    o[2] = fmaf(c.x, w0, o[2]); o[2] = fmaf(c.y, w1, o[2]); o[2] = fmaf(c.z, w2, o[2]); o[2] = fmaf(c.w, w3, o[2]);
    o[3] = fmaf(d.x, w0, o[3]); o[3] = fmaf(d.y, w1, o[3]); o[3] = fmaf(d.z, w2, o[3]); o[3] = fmaf(d.w, w3, o[3]);
  }
}

__global__ __attribute__((amdgpu_waves_per_eu(2)))
__launch_bounds__(THREADS) void rld_kernel(Params P) {
  __shared__ float lds[LDSF];
  const int b = blockIdx.x;
  const int tid = (int)threadIdx.x;
  const int lane = tid & 63;
  const int wave = tid >> 6;
  const int cc = lane & 31;
  const int c16 = lane & 15;

  float* UT = lds + OFF_UT;
  float* VT = lds + OFF_VT;
  float* AG = lds + OFF_AG;
  float* sBn = lds + OFF_BN + wave * 256;   // wave-private bounce
  float* src = lds + OFF_BN;                // A1 only (before bounce use)
  const float* wlt2 = lds + OFF_NW;
  const float* wlt3 = lds + OFF_NW + 4096;
  const float* wlt4 = lds + OFF_NW + 6144;
  const float* wlt5 = lds + OFF_NW + 6656;
  const int i0 = wave, i1 = wave + 8, i2 = wave + 16, i3 = wave + 24;
  const int h33 = lane * 33;
  const float* zb = P.z + (size_t)b * NT * NO * NEE;

  // stage step-invariant small node weights once (read from s=1 on)
  stageN(lds + OFF_NW,        P.lt2w, 1024, tid);
  stageN(lds + OFF_NW + 4096, P.lt3w,  512, tid);
  stageN(lds + OFF_NW + 6144, P.lt4w,  128, tid);
  stageN(lds + OFF_NW + 6656, P.lt5w,  256, tid);

  // ===== A1: src[32,512] @ {ee1u, ee1v, ne1src}; 8 chunks of [32][64] =====
  float au[4] = {0,0,0,0}, av[4] = {0,0,0,0}, s1r[4] = {0,0,0,0};
  for (int qq = 0; qq < 8; ++qq) {
    __syncthreads();                    // prior chunk readers done
    for (int idx = tid; idx < 2048; idx += THREADS) {
      int i = idx >> 6, kk = idx & 63;
      int k = qq * 64 + kk, t = k >> 5, e = k & 31;
      float v = zb[(t * NO + i) * NEE + e];
      if (t > 0) v -= zb[((t - 1) * NO + i) * NEE + e];
      src[i * 64 + kk] = v;
    }
    __syncthreads();                    // chunk visible
    for (int c = 0; c < 2; ++c) {
      int r0 = qq * 64 + c * 32;
      const float* x0 = src + i0 * 64 + c * 32;
      const float* x1 = src + i1 * 64 + c * 32;
      const float* x2 = src + i2 * 64 + c * 32;
      const float* x3 = src + i3 * 64 + c * 32;
      dense4L<8>(x0, x1, x2, x3, P.ee1w + (size_t)r0 * 64,         64, lane, au);
      dense4L<8>(x0, x1, x2, x3, P.ee1w + (size_t)(512 + r0) * 64, 64, lane, av);
      dense4L<8>(x0, x1, x2, x3, P.ne1w + (size_t)r0 * 64,         64, lane, s1r);
    }
  }
  {
    float eb1 = P.ee1b[lane];           // fold b1 into u^T
    UT[h33 + i0] = au[0] + eb1; UT[h33 + i1] = au[1] + eb1;
    UT[h33 + i2] = au[2] + eb1; UT[h33 + i3] = au[3] + eb1;
    VT[h33 + i0] = av[0]; VT[h33 + i1] = av[1];
    VT[h33 + i2] = av[2]; VT[h33 + i3] = av[3];
  }
  for (int z = tid; z < 2048; z += THREADS) AG[z] = 0.f;

  // pair-MLP weight COLUMNS in registers (lane = output channel)
  float w2c[64], w3c[64];
#pragma unroll
  for (int h = 0; h < 64; ++h) w2c[h] = P.ee2w[h * 64 + lane];
#pragma unroll
  for (int h = 0; h < 64; ++h) w3c[h] = P.ee3w[h * 64 + lane];
  float b2c = P.ee2b[lane], b3c = P.ee3b[lane];
  __syncthreads();                      // UT/VT/AG/NW published

  const int tf = P.tf;
  float zci[4] = {0, 0, 0, 0};
  float* outb = P.out + (size_t)b * tf * NO * NEE;

  for (int s = 0; s <= tf; ++s) {
    // ===== pair phase: 62 pairs/wave, 2 at a time; zero loads in inner loops =====
    {
      int pi = 0, rem = wave * 62;
      while (rem >= 31 - pi) { rem -= 31 - pi; ++pi; }
      int pj = pi + 1 + rem;
#pragma unroll 1
      for (int pp = 0; pp < 31; ++pp) {
        const int iA = pi, jA = pj;
        ++pj; if (pj == 32) { ++pi; pj = pi + 1; }
        const int iB = pi, jB = pj;
        ++pj; if (pj == 32) { ++pi; pj = pi + 1; }
        float xA = fmaxf(UT[h33 + iA] + VT[h33 + jA], 0.f);  // lane = h
        float xB = fmaxf(UT[h33 + iB] + VT[h33 + jB], 0.f);
        float a0 = b2c, a1 = 0.f, c0 = b2c, c1 = 0.f;
#pragma unroll
        for (int h = 0; h < 64; h += 2) {
          a0 = fmaf(rl(xA, h),     w2c[h],     a0);
          a1 = fmaf(rl(xA, h + 1), w2c[h + 1], a1);
          c0 = fmaf(rl(xB, h),     w2c[h],     c0);
          c1 = fmaf(rl(xB, h + 1), w2c[h + 1], c1);
        }
        float yA = fmaxf(a0 + a1, 0.f);                      // lane = h for L3
        float yB = fmaxf(c0 + c1, 0.f);
        float e0 = b3c, e1 = 0.f, f0 = b3c, f1 = 0.f;
#pragma unroll
        for (int h = 0; h < 64; h += 2) {
          e0 = fmaf(rl(yA, h),     w3c[h],     e0);
          e1 = fmaf(rl(yA, h + 1), w3c[h + 1], e1);
          f0 = fmaf(rl(yB, h),     w3c[h],     f0);
          f1 = fmaf(rl(yB, h + 1), w3c[h + 1], f1);
        }
        float eA = e0 + e1, eB = f0 + f1;
        atomicAdd(&AG[iA * 64 + lane],  eA);
        atomicAdd(&AG[jA * 64 + lane], -eA);
        atomicAdd(&AG[iB * 64 + lane],  eB);
        atomicAdd(&AG[jB * 64 + lane], -eB);
      }
    }
    __syncthreads();                    // B1: agg complete

    if (s == 0) {
      // ----- ne node MLP -> zci -----
      float nb1 = P.ne1b[lane], nb2 = P.ne2b[lane];
      float nb3 = P.ne3b[cc],   nb4 = P.ne4b[cc];
      float o1[4] = {s1r[0] + nb1, s1r[1] + nb1, s1r[2] + nb1, s1r[3] + nb1};
      dense4L<16>(AG + i0 * 64, AG + i1 * 64, AG + i2 * 64, AG + i3 * 64,
                  P.ne1w + (size_t)512 * 64, 64, lane, o1);
      sBn[lane] = frelu(o1[0]); sBn[64 + lane] = frelu(o1[1]);
      sBn[128 + lane] = frelu(o1[2]); sBn[192 + lane] = frelu(o1[3]);
      float o2[4] = {nb2, nb2, nb2, nb2};
      dense4L<16>(sBn, sBn + 64, sBn + 128, sBn + 192, P.ne2w, 64, lane, o2);
      sBn[lane] = frelu(o2[0]); sBn[64 + lane] = frelu(o2[1]);
      sBn[128 + lane] = frelu(o2[2]); sBn[192 + lane] = frelu(o2[3]);
      float o3[4] = {nb3, nb3, nb3, nb3};
      dense4L<16>(sBn, sBn + 64, sBn + 128, sBn + 192, P.ne3w, 32, cc, o3);
      sBn[cc] = frelu(o3[0]); sBn[64 + cc] = frelu(o3[1]);
      sBn[128 + cc] = frelu(o3[2]); sBn[192 + cc] = frelu(o3[3]);
      float o4[4] = {nb4, nb4, nb4, nb4};
      dense4L<8>(sBn, sBn + 64, sBn + 128, sBn + 192, P.ne4w, 32, cc, o4);
      zci[0] = (lane < 32) ? zb[(15 * NO + i0) * NEE + lane] : o4[0];
      zci[1] = (lane < 32) ? zb[(15 * NO + i1) * NEE + lane] : o4[1];
      zci[2] = (lane < 32) ? zb[(15 * NO + i2) * NEE + lane] : o4[2];
      zci[3] = (lane < 32) ? zb[(15 * NO + i3) * NEE + lane] : o4[3];
    } else {
      // ----- lt node MLP (sBn holds zci bounce from prep(s-1)) -----
      float lb1 = P.lt1b[lane], lb2 = P.lt2b[lane];
      float lb3 = P.lt3b[cc],   lb4 = P.lt4b[c16], lb5 = P.lt5b[lane];
      float o1[4] = {lb1, lb1, lb1, lb1};
      dense4L<16>(sBn, sBn + 64, sBn + 128, sBn + 192, P.lt1w, 64, lane, o1);
      dense4L<16>(AG + i0 * 64, AG + i1 * 64, AG + i2 * 64, AG + i3 * 64,
                  P.lt1w + (size_t)64 * 64, 64, lane, o1);
      sBn[lane] = frelu(o1[0]); sBn[64 + lane] = frelu(o1[1]);
      sBn[128 + lane] = frelu(o1[2]); sBn[192 + lane] = frelu(o1[3]);
      float o2[4] = {lb2, lb2, lb2, lb2};
      dense4L<16>(sBn, sBn + 64, sBn + 128, sBn + 192, wlt2, 64, lane, o2);
      sBn[lane] = frelu(o2[0]); sBn[64 + lane] = frelu(o2[1]);
      sBn[128 + lane] = frelu(o2[2]); sBn[192 + lane] = frelu(o2[3]);
      float o3[4] = {lb3, lb3, lb3, lb3};
      dense4L<16>(sBn, sBn + 64, sBn + 128, sBn + 192, wlt3, 32, cc, o3);
      sBn[cc] = frelu(o3[0]); sBn[64 + cc] = frelu(o3[1]);
      sBn[128 + cc] = frelu(o3[2]); sBn[192 + cc] = frelu(o3[3]);
      float o4[4] = {lb4, lb4, lb4, lb4};
      dense4L<8>(sBn, sBn + 64, sBn + 128, sBn + 192, wlt4, 16, c16, o4);
      sBn[c16] = frelu(o4[0]); sBn[64 + c16] = frelu(o4[1]);
      sBn[128 + c16] = frelu(o4[2]); sBn[192 + c16] = frelu(o4[3]);
      float o5[4] = {lb5, lb5, lb5, lb5};
      dense4L<4>(sBn, sBn + 64, sBn + 128, sBn + 192, wlt5, 64, lane, o5);
      zci[0] += o5[0]; zci[1] += o5[1]; zci[2] += o5[2]; zci[3] += o5[3];
      int t = s - 1;
      if (lane < 32) {
        outb[(t * NO + i0) * NEE + lane] = zci[0];
        outb[(t * NO + i1) * NEE + lane] = zci[1];
        outb[(t * NO + i2) * NEE + lane] = zci[2];
        outb[(t * NO + i3) * NEE + lane] = zci[3];
      }
    }
    __syncthreads();                    // B2: AG readers done

    if (s < tf) {
      if (s == 0) {                     // switch pair weights ee -> le (once)
#pragma unroll
        for (int h = 0; h < 64; ++h) w2c[h] = P.le2w[h * 64 + lane];
#pragma unroll
        for (int h = 0; h < 64; ++h) w3c[h] = P.le3w[h * 64 + lane];
        b2c = P.le2b[lane]; b3c = P.le3b[lane];
      }
      for (int z = tid; z < 2048; z += THREADS) AG[z] = 0.f;
      sBn[lane] = zci[0]; sBn[64 + lane] = zci[1];
      sBn[128 + lane] = zci[2]; sBn[192 + lane] = zci[3];
      float gb1 = P.le1b[lane];
      float ou[4] = {0,0,0,0}, ov[4] = {0,0,0,0};
      dense4L<16>(sBn, sBn + 64, sBn + 128, sBn + 192, P.le1w,        64, lane, ou);
      dense4L<16>(sBn, sBn + 64, sBn + 128, sBn + 192, P.le1w + 4096, 64, lane, ov);
      UT[h33 + i0] = ou[0] + gb1; UT[h33 + i1] = ou[1] + gb1;
      UT[h33 + i2] = ou[2] + gb1; UT[h33 + i3] = ou[3] + gb1;
      VT[h33 + i0] = ov[0]; VT[h33 + i1] = ov[1];
      VT[h33 + i2] = ov[2]; VT[h33 + i3] = ov[3];
    }
    __syncthreads();                    // B3: UT/VT + agg-zero published
  }
}

extern "C" void kernel_launch(void* const* d_in, const int* in_sizes, int n_in,
                              void* d_out, int out_size, void* d_ws, size_t ws_size,
                              hipStream_t stream) {
  (void)in_sizes; (void)n_in; (void)d_ws; (void)ws_size;
  Params P;
  int q = 0;
  P.z    = (fp)d_in[q++];
  P.ee1w = (fp)d_in[q++]; P.ee1b = (fp)d_in[q++];
  P.ee2w = (fp)d_in[q++]; P.ee2b = (fp)d_in[q++];
  P.ee3w = (fp)d_in[q++]; P.ee3b = (fp)d_in[q++];
  P.ne1w = (fp)d_in[q++]; P.ne1b = (fp)d_in[q++];
  P.ne2w = (fp)d_in[q++]; P.ne2b = (fp)d_in[q++];
  P.ne3w = (fp)d_in[q++]; P.ne3b = (fp)d_in[q++];
  P.ne4w = (fp)d_in[q++]; P.ne4b = (fp)d_in[q++];
  P.le1w = (fp)d_in[q++]; P.le1b = (fp)d_in[q++];
  P.le2w = (fp)d_in[q++]; P.le2b = (fp)d_in[q++];
  P.le3w = (fp)d_in[q++]; P.le3b = (fp)d_in[q++];
  P.lt1w = (fp)d_in[q++]; P.lt1b = (fp)d_in[q++];
  P.lt2w = (fp)d_in[q++]; P.lt2b = (fp)d_in[q++];
  P.lt3w = (fp)d_in[q++]; P.lt3b = (fp)d_in[q++];
  P.lt4w = (fp)d_in[q++]; P.lt4b = (fp)d_in[q++];
  P.lt5w = (fp)d_in[q++]; P.lt5b = (fp)d_in[q++];
  P.out = (float*)d_out;
  P.tf = out_size / (NB * NO * NEE);
  if (P.tf < 1) P.tf = 1;
  hipLaunchKernelGGL(rld_kernel, dim3(NB), dim3(THREADS), 0, stream, P);
}